// Round 14
// baseline (125.121 us; speedup 1.0000x reference)
//
#include <hip/hip_runtime.h>

typedef _Float16 f16;
typedef _Float16 f16x8 __attribute__((ext_vector_type(8)));
typedef float f32x4 __attribute__((ext_vector_type(4)));

#define MFMA16(a, b, c) __builtin_amdgcn_mfma_f32_16x16x32_f16((a), (b), (c), 0, 0, 0)

constexpr int SEQ   = 16;
constexpr int PLEN  = 15;
constexpr int BATCH = 32768;
constexpr int POSE  = 34;
constexpr int HD    = 64;
constexpr int GRPS  = 4;     // four independent 16-row chains per wave, R6 phase SHAPE (not R7 stagger)
constexpr int ROWS  = 16;    // rows per chain (single m-fragment)
constexpr int BROWS = GRPS * ROWS;  // 64 rows per block -> grid 512
constexpr int XROW  = 136;   // [h 0..63 | x 64..97 | 1.0 @98 | 0..127 | pad]

constexpr float LOG2E   = 1.4426950408889634f;
constexpr float LOG2E2  = 2.8853900817779268f;
constexpr float NLOG2E2 = -2.8853900817779268f;

__device__ __forceinline__ float rcpf(float x)   { return __builtin_amdgcn_rcpf(x); }
__device__ __forceinline__ float exp2f_(float x) { return __builtin_amdgcn_exp2f(x); }

// R13 (merged-rcp nonlin, R6 two-barrier decoder) with GRPS 2x32 -> 4x16 rows.
__global__ __launch_bounds__(256, 2)
void lstm14(const float* __restrict__ obs,
            const float* __restrict__ Wih_e, const float* __restrict__ Whh_e,
            const float* __restrict__ b_e,
            const float* __restrict__ Wih_d, const float* __restrict__ Whh_d,
            const float* __restrict__ b_d,
            const float* __restrict__ fc_w, const float* __restrict__ fc_b,
            float* __restrict__ out)
{
    // [dbuf][chain][row][XROW] — 34816 B
    __shared__ f16 bfr[2 * GRPS * ROWS * XROW];

    const int tid  = threadIdx.x;
    const int lane = tid & 63;
    const int q    = tid >> 6;     // gate-column split (j = q*16 + l15)
    const int l15  = lane & 15;
    const int l4   = lane >> 4;
    const int blkbase = blockIdx.x * BROWS;

    f16x8 Bw[4][4];
    auto loadB = [&](const float* __restrict__ Wih, const float* __restrict__ Whh,
                     const float* __restrict__ b) {
        #pragma unroll
        for (int gg = 0; gg < 4; ++gg) {
            const int r = (gg * 4 + q) * 16 + l15;
            const float sc = (gg == 2) ? LOG2E2 : LOG2E;
            #pragma unroll
            for (int kf = 0; kf < 2; ++kf) {
                const float* src = Whh + r * HD + kf * 32 + l4 * 8;
                #pragma unroll
                for (int j = 0; j < 8; ++j) Bw[gg][kf][j] = (f16)(src[j] * sc);
            }
            {
                const float* src = Wih + r * POSE + l4 * 8;
                #pragma unroll
                for (int j = 0; j < 8; ++j) Bw[gg][2][j] = (f16)(src[j] * sc);
            }
            #pragma unroll
            for (int j = 0; j < 8; ++j) {
                const int k = 96 + l4 * 8 + j;
                float v = 0.f;
                if (k < 98)       v = Wih[r * POSE + (k - 64)];
                else if (k == 98) v = b[r];
                Bw[gg][3][j] = (f16)(v * sc);
            }
        }
    };
    loadB(Wih_e, Whh_e, b_e);

    auto stage_x = [&](int ts, int dstbuf) {
        const float* src = obs + ((size_t)ts * BATCH + blkbase) * POSE;  // 2176 contiguous f32
        #pragma unroll
        for (int it = 0; it < 9; ++it) {
            int i = it * 256 + tid;
            if (i < BROWS * POSE) {
                int row = i / POSE, col = i - row * POSE;
                bfr[((dstbuf * GRPS + (row >> 4)) * ROWS + (row & 15)) * XROW + HD + col] = (f16)src[i];
            }
        }
    };

    // fc weights / bias, register-resident
    const int  p    = q * 16 + l15;
    const bool fcok = (q < 3);
    f16x8 Bfc[2];
    #pragma unroll
    for (int kf = 0; kf < 2; ++kf)
        #pragma unroll
        for (int j = 0; j < 8; ++j)
            Bfc[kf][j] = (f16)((fcok && p < POSE) ? fc_w[p * HD + kf * 32 + l4 * 8 + j] : 0.f);
    const float fcb = (fcok && p < POSE) ? fc_b[p] : 0.f;

    // init: h0 = 0, bias col = 1.0
    for (int i = tid; i < 2 * GRPS * ROWS * XROW; i += 256) {
        int c = i % XROW;
        bfr[i] = (c == 98) ? (f16)1.0f : (f16)0.0f;
    }
    __syncthreads();
    stage_x(0, 0);
    __syncthreads();

    f32x4 cst[GRPS];
    #pragma unroll
    for (int c = 0; c < GRPS; ++c) cst[c] = (f32x4)0.f;

    auto ldA = [&](int c, int sb, f16x8 (&a)[4]) {
        #pragma unroll
        for (int kf = 0; kf < 4; ++kf)
            a[kf] = *(const f16x8*)&bfr[((sb * GRPS + c) * ROWS + l15) * XROW + kf * 32 + l4 * 8];
    };
    auto gates = [&](const f16x8 (&a)[4], f32x4 (&acc)[4]) {
        #pragma unroll
        for (int gg = 0; gg < 4; ++gg) acc[gg] = (f32x4)0.f;
        #pragma unroll
        for (int kf = 0; kf < 4; ++kf)
            #pragma unroll
            for (int gg = 0; gg < 4; ++gg)
                acc[gg] = MFMA16(a[kf], Bw[gg][kf], acc[gg]);
    };
    // merged-rcp nonlin (R13-validated): 5 exp2 + 2 rcp per element
    auto nonlin = [&](int c, f32x4 (&acc)[4], int db) {
        #pragma unroll
        for (int r = 0; r < 4; ++r) {
            float Ei = exp2f_(-acc[0][r]);
            float Ef = exp2f_(-acc[1][r]);
            float Eg = exp2f_(-acc[2][r]);   // e^{-2g} (pre-scaled 2log2e)
            float Eo = exp2f_(-acc[3][r]);
            float pf = 1.f + Ef;
            float P  = (1.f + Ei) * (1.f + Eg);
            float cc = (cst[c][r] * P + (1.f - Eg) * pf) * rcpf(pf * P);
            float Ec = exp2f_(cc * NLOG2E2);
            float h  = (1.f - Ec) * rcpf((1.f + Eo) * (1.f + Ec));
            cst[c][r] = cc;
            bfr[((db * GRPS + c) * ROWS + l4 * 4 + r) * XROW + q * 16 + l15] = (f16)h;
        }
    };
    auto fc_step = [&](int c, int srcbuf, int t) {  // out + f16 feedback (R6 structure)
        if (!fcok) return;
        f16x8 ah[2];
        #pragma unroll
        for (int kf = 0; kf < 2; ++kf)
            ah[kf] = *(const f16x8*)&bfr[((srcbuf * GRPS + c) * ROWS + l15) * XROW + kf * 32 + l4 * 8];
        f32x4 o = {fcb, fcb, fcb, fcb};
        o = MFMA16(ah[0], Bfc[0], o);
        o = MFMA16(ah[1], Bfc[1], o);
        if (p < POSE) {
            float* ob = out + ((size_t)t * BATCH + blkbase + c * ROWS) * POSE;
            #pragma unroll
            for (int r = 0; r < 4; ++r) {
                int r0 = l4 * 4 + r;
                ob[r0 * POSE + p] = o[r];
                bfr[((srcbuf * GRPS + c) * ROWS + r0) * XROW + HD + p] = (f16)o[r];  // feedback
            }
        }
    };

    int cur = 0;

    // ======== encoder: 16 steps — R6 SHAPE: all ld+gates, stage_x, all nonlin ========
    #pragma unroll 1
    for (int s = 0; s < SEQ; ++s) {
        const int nxt = cur ^ 1;
        f16x8 a0[4], a1[4], a2[4], a3[4];
        f32x4 acc0[4], acc1[4], acc2[4], acc3[4];
        ldA(0, cur, a0); gates(a0, acc0);
        ldA(1, cur, a1); gates(a1, acc1);
        ldA(2, cur, a2); gates(a2, acc2);
        ldA(3, cur, a3); gates(a3, acc3);
        { int ts = s + 1 < 15 ? s + 1 : 15; stage_x(ts, nxt); }
        nonlin(0, acc0, nxt);
        nonlin(1, acc1, nxt);
        nonlin(2, acc2, nxt);
        nonlin(3, acc3, nxt);
        __syncthreads();
        cur = nxt;
    }

    // ======== decoder: 15 steps (R6/R13 two-barrier structure, per chain) ========
    loadB(Wih_d, Whh_d, b_d);
    #pragma unroll 1
    for (int t = 0; t < PLEN; ++t) {
        const int nxt = cur ^ 1;
        f16x8 a0[4], a1[4], a2[4], a3[4];
        f32x4 acc0[4], acc1[4], acc2[4], acc3[4];
        ldA(0, cur, a0); gates(a0, acc0);
        ldA(1, cur, a1); gates(a1, acc1);
        ldA(2, cur, a2); gates(a2, acc2);
        ldA(3, cur, a3); gates(a3, acc3);
        nonlin(0, acc0, nxt);
        nonlin(1, acc1, nxt);
        nonlin(2, acc2, nxt);
        nonlin(3, acc3, nxt);
        __syncthreads();              // h complete -> fc reads full 64-wide h
        fc_step(0, nxt, t);
        fc_step(1, nxt, t);
        fc_step(2, nxt, t);
        fc_step(3, nxt, t);
        __syncthreads();              // feedback visible before next step's A-reads
        cur = nxt;
    }
}

extern "C" void kernel_launch(void* const* d_in, const int* in_sizes, int n_in,
                              void* d_out, int out_size, void* d_ws, size_t ws_size,
                              hipStream_t stream) {
    const float* obs   = (const float*)d_in[0];
    const float* Wih_e = (const float*)d_in[1];
    const float* Whh_e = (const float*)d_in[2];
    const float* b_e   = (const float*)d_in[3];
    const float* Wih_d = (const float*)d_in[4];
    const float* Whh_d = (const float*)d_in[5];
    const float* b_d   = (const float*)d_in[6];
    const float* fc_w  = (const float*)d_in[7];
    const float* fc_b  = (const float*)d_in[8];
    float* out = (float*)d_out;

    lstm14<<<dim3(BATCH / BROWS), dim3(256), 0, stream>>>(
        obs, Wih_e, Whh_e, b_e, Wih_d, Whh_d, b_d, fc_w, fc_b, out);
}

// Round 16
// 121.398 us; speedup vs baseline: 1.0307x; 1.0307x over previous
//
#include <hip/hip_runtime.h>

typedef _Float16 f16;
typedef __fp16 fp16x2 __attribute__((ext_vector_type(2)));   // native cvt_pkrtz result type
typedef _Float16 f16x8 __attribute__((ext_vector_type(8)));
typedef float f32x4 __attribute__((ext_vector_type(4)));

#define MFMA16(a, b, c) __builtin_amdgcn_mfma_f32_16x16x32_f16((a), (b), (c), 0, 0, 0)

constexpr int SEQ   = 16;
constexpr int PLEN  = 15;
constexpr int BATCH = 32768;
constexpr int POSE  = 34;
constexpr int HD    = 64;
constexpr int GRPS  = 2;     // two independent 32-row chains per wave (R6/R13 champion)
constexpr int ROWS  = 32;
constexpr int BROWS = GRPS * ROWS;  // 64 rows per block -> grid 512
constexpr int XROW  = 136;   // [h 0..63 | x 64..97 | 1.0 @98 | 0..127 | pad]

constexpr float LOG2E   = 1.4426950408889634f;
constexpr float LOG2E2  = 2.8853900817779268f;
constexpr float NLOG2E2 = -2.8853900817779268f;

__device__ __forceinline__ float rcpf(float x)   { return __builtin_amdgcn_rcpf(x); }
__device__ __forceinline__ float exp2f_(float x) { return __builtin_amdgcn_exp2f(x); }

// R13 champion + (1) pairwise-vectorized stage_x (cvt_pkrtz + ds_write_b32)
//               + (2) s_setprio(1) around the gate-MFMA clusters (T5).
__global__ __launch_bounds__(256, 2)
void lstm15(const float* __restrict__ obs,
            const float* __restrict__ Wih_e, const float* __restrict__ Whh_e,
            const float* __restrict__ b_e,
            const float* __restrict__ Wih_d, const float* __restrict__ Whh_d,
            const float* __restrict__ b_d,
            const float* __restrict__ fc_w, const float* __restrict__ fc_b,
            float* __restrict__ out)
{
    // [dbuf][grp][row][XROW] activation rows — 34816 B
    __shared__ f16 bfr[2 * GRPS * ROWS * XROW];

    const int tid  = threadIdx.x;
    const int lane = tid & 63;
    const int q    = tid >> 6;     // gate-column split (j = q*16 + l15)
    const int l15  = lane & 15;
    const int l4   = lane >> 4;
    const int blkbase = blockIdx.x * BROWS;

    f16x8 Bw[4][4];
    auto loadB = [&](const float* __restrict__ Wih, const float* __restrict__ Whh,
                     const float* __restrict__ b) {
        #pragma unroll
        for (int gg = 0; gg < 4; ++gg) {
            const int r = (gg * 4 + q) * 16 + l15;
            const float sc = (gg == 2) ? LOG2E2 : LOG2E;
            #pragma unroll
            for (int kf = 0; kf < 2; ++kf) {
                const float* src = Whh + r * HD + kf * 32 + l4 * 8;
                #pragma unroll
                for (int j = 0; j < 8; ++j) Bw[gg][kf][j] = (f16)(src[j] * sc);
            }
            {
                const float* src = Wih + r * POSE + l4 * 8;
                #pragma unroll
                for (int j = 0; j < 8; ++j) Bw[gg][2][j] = (f16)(src[j] * sc);
            }
            #pragma unroll
            for (int j = 0; j < 8; ++j) {
                const int k = 96 + l4 * 8 + j;
                float v = 0.f;
                if (k < 98)       v = Wih[r * POSE + (k - 64)];
                else if (k == 98) v = b[r];
                Bw[gg][3][j] = (f16)(v * sc);
            }
        }
    };
    loadB(Wih_e, Whh_e, b_e);

    // pairwise-vectorized x staging: POSE even => (col,col+1) pairs never cross rows.
    // float2 load (8B-aligned) -> v_cvt_pkrtz -> 32-bit LDS store.
    auto stage_x = [&](int ts, int dstbuf) {
        const float* src = obs + ((size_t)ts * BATCH + blkbase) * POSE;
        #pragma unroll
        for (int it = 0; it < 5; ++it) {
            int ip = it * 256 + tid;            // pair index
            if (ip < BROWS * POSE / 2) {
                int i = ip * 2;
                int row = i / POSE, col = i - row * POSE;   // col even
                float2 v = *(const float2*)&src[i];
                fp16x2 h2 = __builtin_amdgcn_cvt_pkrtz(v.x, v.y);
                *(fp16x2*)&bfr[((dstbuf * GRPS + (row >> 5)) * ROWS + (row & 31)) * XROW + HD + col] = h2;
            }
        }
    };

    // fc weights / bias, register-resident
    const int  p    = q * 16 + l15;
    const bool fcok = (q < 3);
    f16x8 Bfc[2];
    #pragma unroll
    for (int kf = 0; kf < 2; ++kf)
        #pragma unroll
        for (int j = 0; j < 8; ++j)
            Bfc[kf][j] = (f16)((fcok && p < POSE) ? fc_w[p * HD + kf * 32 + l4 * 8 + j] : 0.f);
    const float fcb = (fcok && p < POSE) ? fc_b[p] : 0.f;

    // init: h0 = 0, bias col = 1.0
    for (int i = tid; i < 2 * GRPS * ROWS * XROW; i += 256) {
        int c = i % XROW;
        bfr[i] = (c == 98) ? (f16)1.0f : (f16)0.0f;
    }
    __syncthreads();
    stage_x(0, 0);
    __syncthreads();

    f32x4 cst[GRPS][2];
    #pragma unroll
    for (int g = 0; g < GRPS; ++g) { cst[g][0] = (f32x4)0.f; cst[g][1] = (f32x4)0.f; }

    auto ldA = [&](int grp, int srcbuf, f16x8 (&a)[2][4]) {
        #pragma unroll
        for (int mf = 0; mf < 2; ++mf)
            #pragma unroll
            for (int kf = 0; kf < 4; ++kf)
                a[mf][kf] = *(const f16x8*)&bfr[((srcbuf * GRPS + grp) * ROWS + mf * 16 + l15) * XROW + kf * 32 + l4 * 8];
    };
    auto gates = [&](const f16x8 (&a)[2][4], f32x4 (&acc)[2][4]) {
        #pragma unroll
        for (int mf = 0; mf < 2; ++mf)
            #pragma unroll
            for (int gg = 0; gg < 4; ++gg) acc[mf][gg] = (f32x4)0.f;
        #pragma unroll
        for (int kf = 0; kf < 4; ++kf)
            #pragma unroll
            for (int gg = 0; gg < 4; ++gg) {
                acc[0][gg] = MFMA16(a[0][kf], Bw[gg][kf], acc[0][gg]);
                acc[1][gg] = MFMA16(a[1][kf], Bw[gg][kf], acc[1][gg]);
            }
    };
    // merged-rcp nonlin (R13-validated): 5 exp2 + 2 rcp per element
    auto nonlin = [&](int grp, f32x4 (&acc)[2][4], int dstbuf) {
        #pragma unroll
        for (int mf = 0; mf < 2; ++mf) {
            #pragma unroll
            for (int r = 0; r < 4; ++r) {
                float Ei = exp2f_(-acc[mf][0][r]);
                float Ef = exp2f_(-acc[mf][1][r]);
                float Eg = exp2f_(-acc[mf][2][r]);   // e^{-2g} (pre-scaled 2log2e)
                float Eo = exp2f_(-acc[mf][3][r]);
                float pf = 1.f + Ef;
                float P  = (1.f + Ei) * (1.f + Eg);
                float cc = (cst[grp][mf][r] * P + (1.f - Eg) * pf) * rcpf(pf * P);
                float Ec = exp2f_(cc * NLOG2E2);
                float h  = (1.f - Ec) * rcpf((1.f + Eo) * (1.f + Ec));
                cst[grp][mf][r] = cc;
                bfr[((dstbuf * GRPS + grp) * ROWS + mf * 16 + l4 * 4 + r) * XROW + q * 16 + l15] = (f16)h;
            }
        }
    };
    auto fc_step = [&](int grp, int srcbuf, int t) {
        if (!fcok) return;
        f16x8 ah[2][2];
        #pragma unroll
        for (int mf = 0; mf < 2; ++mf)
            #pragma unroll
            for (int kf = 0; kf < 2; ++kf)
                ah[mf][kf] = *(const f16x8*)&bfr[((srcbuf * GRPS + grp) * ROWS + mf * 16 + l15) * XROW + kf * 32 + l4 * 8];
        f32x4 o0 = {fcb, fcb, fcb, fcb}, o1 = {fcb, fcb, fcb, fcb};
        #pragma unroll
        for (int kf = 0; kf < 2; ++kf) {
            o0 = MFMA16(ah[0][kf], Bfc[kf], o0);
            o1 = MFMA16(ah[1][kf], Bfc[kf], o1);
        }
        if (p < POSE) {
            float* ob = out + ((size_t)t * BATCH + blkbase + grp * ROWS) * POSE;
            #pragma unroll
            for (int r = 0; r < 4; ++r) {
                int r0 = l4 * 4 + r, r1 = 16 + l4 * 4 + r;
                ob[r0 * POSE + p] = o0[r];
                ob[r1 * POSE + p] = o1[r];
                bfr[((srcbuf * GRPS + grp) * ROWS + r0) * XROW + HD + p] = (f16)o0[r];  // feedback
                bfr[((srcbuf * GRPS + grp) * ROWS + r1) * XROW + HD + p] = (f16)o1[r];
            }
        }
    };

    int cur = 0;

    // ======== encoder: 16 steps, R6 phase shape, 1 barrier/step ========
    #pragma unroll 1
    for (int s = 0; s < SEQ; ++s) {
        const int nxt = cur ^ 1;
        f16x8 aA[2][4], aB[2][4];
        f32x4 accA[2][4], accB[2][4];
        __builtin_amdgcn_s_setprio(1);          // favor this wave through the MFMA burst (T5)
        ldA(0, cur, aA);
        gates(aA, accA);
        ldA(1, cur, aB);
        gates(aB, accB);
        __builtin_amdgcn_s_setprio(0);
        { int ts = s + 1 < 15 ? s + 1 : 15; stage_x(ts, nxt); }
        nonlin(0, accA, nxt);
        nonlin(1, accB, nxt);
        __syncthreads();
        cur = nxt;
    }

    // ======== decoder: 15 steps (R6/R13 two-barrier structure) ========
    loadB(Wih_d, Whh_d, b_d);
    #pragma unroll 1
    for (int t = 0; t < PLEN; ++t) {
        const int nxt = cur ^ 1;
        f16x8 aA[2][4], aB[2][4];
        f32x4 accA[2][4], accB[2][4];
        __builtin_amdgcn_s_setprio(1);
        ldA(0, cur, aA);
        gates(aA, accA);
        ldA(1, cur, aB);
        gates(aB, accB);
        __builtin_amdgcn_s_setprio(0);
        nonlin(0, accA, nxt);
        nonlin(1, accB, nxt);
        __syncthreads();              // h complete -> fc reads full 64-wide h
        fc_step(0, nxt, t);           // writes out + x-feedback into buf[nxt]
        fc_step(1, nxt, t);
        __syncthreads();              // feedback visible before next step's A-reads
        cur = nxt;
    }
}

extern "C" void kernel_launch(void* const* d_in, const int* in_sizes, int n_in,
                              void* d_out, int out_size, void* d_ws, size_t ws_size,
                              hipStream_t stream) {
    const float* obs   = (const float*)d_in[0];
    const float* Wih_e = (const float*)d_in[1];
    const float* Whh_e = (const float*)d_in[2];
    const float* b_e   = (const float*)d_in[3];
    const float* Wih_d = (const float*)d_in[4];
    const float* Whh_d = (const float*)d_in[5];
    const float* b_d   = (const float*)d_in[6];
    const float* fc_w  = (const float*)d_in[7];
    const float* fc_b  = (const float*)d_in[8];
    float* out = (float*)d_out;

    lstm15<<<dim3(BATCH / BROWS), dim3(256), 0, stream>>>(
        obs, Wih_e, Whh_e, b_e, Wih_d, Whh_d, b_d, fc_w, fc_b, out);
}

// Round 17
// 120.630 us; speedup vs baseline: 1.0372x; 1.0064x over previous
//
#include <hip/hip_runtime.h>

typedef _Float16 f16;
typedef __fp16 fp16x2 __attribute__((ext_vector_type(2)));   // native cvt_pkrtz result type
typedef _Float16 f16x8 __attribute__((ext_vector_type(8)));
typedef float f32x4 __attribute__((ext_vector_type(4)));

#define MFMA16(a, b, c) __builtin_amdgcn_mfma_f32_16x16x32_f16((a), (b), (c), 0, 0, 0)

constexpr int SEQ   = 16;
constexpr int PLEN  = 15;
constexpr int BATCH = 32768;
constexpr int POSE  = 34;
constexpr int HD    = 64;
constexpr int GRPS  = 2;     // two independent 32-row chains per wave (champion structure)
constexpr int ROWS  = 32;
constexpr int BROWS = GRPS * ROWS;  // 64 rows per block -> grid 512
constexpr int XROW  = 136;   // [h 0..63 | x 64..97 | 1.0 @98 | 0..127 | pad]

constexpr float LOG2E   = 1.4426950408889634f;
constexpr float LOG2E2  = 2.8853900817779268f;
constexpr float NLOG2E2 = -2.8853900817779268f;

__device__ __forceinline__ float rcpf(float x)   { return __builtin_amdgcn_rcpf(x); }
__device__ __forceinline__ float exp2f_(float x) { return __builtin_amdgcn_exp2f(x); }

// R16 champion + decoder store-reorder: fc MFMA + LDS feedback BEFORE the 2nd
// barrier; global out-stores AFTER it (o held in regs). Stores drain at the NEXT
// step's first barrier — hidden behind a full gates+nonlin phase (T14 idiom).
__global__ __launch_bounds__(256, 2)
void lstm17(const float* __restrict__ obs,
            const float* __restrict__ Wih_e, const float* __restrict__ Whh_e,
            const float* __restrict__ b_e,
            const float* __restrict__ Wih_d, const float* __restrict__ Whh_d,
            const float* __restrict__ b_d,
            const float* __restrict__ fc_w, const float* __restrict__ fc_b,
            float* __restrict__ out)
{
    // [dbuf][grp][row][XROW] activation rows — 34816 B
    __shared__ f16 bfr[2 * GRPS * ROWS * XROW];

    const int tid  = threadIdx.x;
    const int lane = tid & 63;
    const int q    = tid >> 6;     // gate-column split (j = q*16 + l15)
    const int l15  = lane & 15;
    const int l4   = lane >> 4;
    const int blkbase = blockIdx.x * BROWS;

    f16x8 Bw[4][4];
    auto loadB = [&](const float* __restrict__ Wih, const float* __restrict__ Whh,
                     const float* __restrict__ b) {
        #pragma unroll
        for (int gg = 0; gg < 4; ++gg) {
            const int r = (gg * 4 + q) * 16 + l15;
            const float sc = (gg == 2) ? LOG2E2 : LOG2E;
            #pragma unroll
            for (int kf = 0; kf < 2; ++kf) {
                const float* src = Whh + r * HD + kf * 32 + l4 * 8;
                #pragma unroll
                for (int j = 0; j < 8; ++j) Bw[gg][kf][j] = (f16)(src[j] * sc);
            }
            {
                const float* src = Wih + r * POSE + l4 * 8;
                #pragma unroll
                for (int j = 0; j < 8; ++j) Bw[gg][2][j] = (f16)(src[j] * sc);
            }
            #pragma unroll
            for (int j = 0; j < 8; ++j) {
                const int k = 96 + l4 * 8 + j;
                float v = 0.f;
                if (k < 98)       v = Wih[r * POSE + (k - 64)];
                else if (k == 98) v = b[r];
                Bw[gg][3][j] = (f16)(v * sc);
            }
        }
    };
    loadB(Wih_e, Whh_e, b_e);

    // pairwise-vectorized x staging (R16-validated): float2 -> cvt_pkrtz -> b32 LDS store
    auto stage_x = [&](int ts, int dstbuf) {
        const float* src = obs + ((size_t)ts * BATCH + blkbase) * POSE;
        #pragma unroll
        for (int it = 0; it < 5; ++it) {
            int ip = it * 256 + tid;            // pair index
            if (ip < BROWS * POSE / 2) {
                int i = ip * 2;
                int row = i / POSE, col = i - row * POSE;   // col even
                float2 v = *(const float2*)&src[i];
                fp16x2 h2 = __builtin_amdgcn_cvt_pkrtz(v.x, v.y);
                *(fp16x2*)&bfr[((dstbuf * GRPS + (row >> 5)) * ROWS + (row & 31)) * XROW + HD + col] = h2;
            }
        }
    };

    // fc weights / bias, register-resident
    const int  p    = q * 16 + l15;
    const bool fcok = (q < 3);
    f16x8 Bfc[2];
    #pragma unroll
    for (int kf = 0; kf < 2; ++kf)
        #pragma unroll
        for (int j = 0; j < 8; ++j)
            Bfc[kf][j] = (f16)((fcok && p < POSE) ? fc_w[p * HD + kf * 32 + l4 * 8 + j] : 0.f);
    const float fcb = (fcok && p < POSE) ? fc_b[p] : 0.f;

    // init: h0 = 0, bias col = 1.0
    for (int i = tid; i < 2 * GRPS * ROWS * XROW; i += 256) {
        int c = i % XROW;
        bfr[i] = (c == 98) ? (f16)1.0f : (f16)0.0f;
    }
    __syncthreads();
    stage_x(0, 0);
    __syncthreads();

    f32x4 cst[GRPS][2];
    #pragma unroll
    for (int g = 0; g < GRPS; ++g) { cst[g][0] = (f32x4)0.f; cst[g][1] = (f32x4)0.f; }

    auto ldA = [&](int grp, int srcbuf, f16x8 (&a)[2][4]) {
        #pragma unroll
        for (int mf = 0; mf < 2; ++mf)
            #pragma unroll
            for (int kf = 0; kf < 4; ++kf)
                a[mf][kf] = *(const f16x8*)&bfr[((srcbuf * GRPS + grp) * ROWS + mf * 16 + l15) * XROW + kf * 32 + l4 * 8];
    };
    auto gates = [&](const f16x8 (&a)[2][4], f32x4 (&acc)[2][4]) {
        #pragma unroll
        for (int mf = 0; mf < 2; ++mf)
            #pragma unroll
            for (int gg = 0; gg < 4; ++gg) acc[mf][gg] = (f32x4)0.f;
        #pragma unroll
        for (int kf = 0; kf < 4; ++kf)
            #pragma unroll
            for (int gg = 0; gg < 4; ++gg) {
                acc[0][gg] = MFMA16(a[0][kf], Bw[gg][kf], acc[0][gg]);
                acc[1][gg] = MFMA16(a[1][kf], Bw[gg][kf], acc[1][gg]);
            }
    };
    // merged-rcp nonlin (R13-validated): 5 exp2 + 2 rcp per element
    auto nonlin = [&](int grp, f32x4 (&acc)[2][4], int dstbuf) {
        #pragma unroll
        for (int mf = 0; mf < 2; ++mf) {
            #pragma unroll
            for (int r = 0; r < 4; ++r) {
                float Ei = exp2f_(-acc[mf][0][r]);
                float Ef = exp2f_(-acc[mf][1][r]);
                float Eg = exp2f_(-acc[mf][2][r]);   // e^{-2g} (pre-scaled 2log2e)
                float Eo = exp2f_(-acc[mf][3][r]);
                float pf = 1.f + Ef;
                float P  = (1.f + Ei) * (1.f + Eg);
                float cc = (cst[grp][mf][r] * P + (1.f - Eg) * pf) * rcpf(pf * P);
                float Ec = exp2f_(cc * NLOG2E2);
                float h  = (1.f - Ec) * rcpf((1.f + Eo) * (1.f + Ec));
                cst[grp][mf][r] = cc;
                bfr[((dstbuf * GRPS + grp) * ROWS + mf * 16 + l4 * 4 + r) * XROW + q * 16 + l15] = (f16)h;
            }
        }
    };
    // fc compute + LDS feedback only (pre-barrier); o kept in registers
    auto fc_calc = [&](int grp, int srcbuf, f32x4& o0, f32x4& o1) {
        if (!fcok) return;
        f16x8 ah[2][2];
        #pragma unroll
        for (int mf = 0; mf < 2; ++mf)
            #pragma unroll
            for (int kf = 0; kf < 2; ++kf)
                ah[mf][kf] = *(const f16x8*)&bfr[((srcbuf * GRPS + grp) * ROWS + mf * 16 + l15) * XROW + kf * 32 + l4 * 8];
        o0 = (f32x4){fcb, fcb, fcb, fcb};
        o1 = (f32x4){fcb, fcb, fcb, fcb};
        #pragma unroll
        for (int kf = 0; kf < 2; ++kf) {
            o0 = MFMA16(ah[0][kf], Bfc[kf], o0);
            o1 = MFMA16(ah[1][kf], Bfc[kf], o1);
        }
        if (p < POSE) {
            #pragma unroll
            for (int r = 0; r < 4; ++r) {
                int r0 = l4 * 4 + r, r1 = 16 + l4 * 4 + r;
                bfr[((srcbuf * GRPS + grp) * ROWS + r0) * XROW + HD + p] = (f16)o0[r];  // feedback
                bfr[((srcbuf * GRPS + grp) * ROWS + r1) * XROW + HD + p] = (f16)o1[r];
            }
        }
    };
    // global stores issued post-barrier; drain hidden under next step's gates+nonlin
    auto store_out = [&](int grp, int t, const f32x4& o0, const f32x4& o1) {
        if (!fcok || p >= POSE) return;
        float* ob = out + ((size_t)t * BATCH + blkbase + grp * ROWS) * POSE;
        #pragma unroll
        for (int r = 0; r < 4; ++r) {
            ob[(l4 * 4 + r) * POSE + p]      = o0[r];
            ob[(16 + l4 * 4 + r) * POSE + p] = o1[r];
        }
    };

    int cur = 0;

    // ======== encoder: 16 steps, R6 phase shape, 1 barrier/step ========
    #pragma unroll 1
    for (int s = 0; s < SEQ; ++s) {
        const int nxt = cur ^ 1;
        f16x8 aA[2][4], aB[2][4];
        f32x4 accA[2][4], accB[2][4];
        __builtin_amdgcn_s_setprio(1);          // favor this wave through the MFMA burst (T5)
        ldA(0, cur, aA);
        gates(aA, accA);
        ldA(1, cur, aB);
        gates(aB, accB);
        __builtin_amdgcn_s_setprio(0);
        { int ts = s + 1 < 15 ? s + 1 : 15; stage_x(ts, nxt); }
        nonlin(0, accA, nxt);
        nonlin(1, accB, nxt);
        __syncthreads();
        cur = nxt;
    }

    // ======== decoder: 15 steps, two barriers, stores reordered post-barrier ========
    loadB(Wih_d, Whh_d, b_d);
    #pragma unroll 1
    for (int t = 0; t < PLEN; ++t) {
        const int nxt = cur ^ 1;
        f16x8 aA[2][4], aB[2][4];
        f32x4 accA[2][4], accB[2][4];
        __builtin_amdgcn_s_setprio(1);
        ldA(0, cur, aA);
        gates(aA, accA);
        ldA(1, cur, aB);
        gates(aB, accB);
        __builtin_amdgcn_s_setprio(0);
        nonlin(0, accA, nxt);
        nonlin(1, accB, nxt);
        __syncthreads();              // h complete -> fc reads full 64-wide h
        f32x4 oA0, oA1, oB0, oB1;
        fc_calc(0, nxt, oA0, oA1);    // MFMA + LDS feedback (no global traffic)
        fc_calc(1, nxt, oB0, oB1);
        __syncthreads();              // feedback visible before next step's A-reads
        store_out(0, t, oA0, oA1);    // stores drain at NEXT step's barrier — hidden
        store_out(1, t, oB0, oB1);
        cur = nxt;
    }
}

extern "C" void kernel_launch(void* const* d_in, const int* in_sizes, int n_in,
                              void* d_out, int out_size, void* d_ws, size_t ws_size,
                              hipStream_t stream) {
    const float* obs   = (const float*)d_in[0];
    const float* Wih_e = (const float*)d_in[1];
    const float* Whh_e = (const float*)d_in[2];
    const float* b_e   = (const float*)d_in[3];
    const float* Wih_d = (const float*)d_in[4];
    const float* Whh_d = (const float*)d_in[5];
    const float* b_d   = (const float*)d_in[6];
    const float* fc_w  = (const float*)d_in[7];
    const float* fc_b  = (const float*)d_in[8];
    float* out = (float*)d_out;

    lstm17<<<dim3(BATCH / BROWS), dim3(256), 0, stream>>>(
        obs, Wih_e, Whh_e, b_e, Wih_d, Whh_d, b_d, fc_w, fc_b, out);
}